// Round 13
// baseline (1336.264 us; speedup 1.0000x reference)
//
#include <hip/hip_runtime.h>

// Problem dims
#define BATCH 256
#define TLEN  512
#define DIN   128
#define DFEAT 256
#define DLAT  512
#define G4    2048   // 4*DLAT
#define KCAT  768    // DFEAT + DLAT

typedef __bf16 bf16x8 __attribute__((ext_vector_type(8)));
typedef float f32x4 __attribute__((ext_vector_type(4)));

// ws layout (bytes) -- identical to round 6/9/10/12 (proven)
#define WCAT_OFF   0u          // 768x2048 bf16 frag-linear: 3,145,728
#define WENC_OFF   3145728u    // 128x256  bf16 frag-linear: 65,536
#define ENC_OFF    3211264u    // enc bf16 [T][B][256]: 67,108,864
#define H_OFF      70320128u   // h dbuf bf16 [2][256][512]: 524,288
#define FLAG_OFF   70844416u   // flags: (grp*16+widx)*16 uints (64B lines): 16,384

__device__ __forceinline__ float sigf(float x)  { return 1.0f / (1.0f + __expf(-x)); }
__device__ __forceinline__ float tanhfast(float x){ return 2.0f / (1.0f + __expf(-2.0f * x)) - 1.0f; }
__device__ __forceinline__ unsigned short bfb(float f) {
    __bf16 b = (__bf16)f;
    return __builtin_bit_cast(unsigned short, b);
}

// ---------------------------------------------------------------------------
// Weight prep: bf16 fragment-linear copies of [W_x;W_h] (768x2048) and W_enc.
// wcat layout (wave-owns-all-gates, r9-proven): chunk cid = ((((widx*4 + np)
// *2 + nf)*24 + ks)*64 + l) holds B[k = ks*32+(l>>4)*8 .. +8][col] with
//   cc = l&15;  gate = (cc<8) ? (nf?2:0) : (nf?3:1);
//   col = gate*512 + widx*32 + np*8 + (cc&7).
// ---------------------------------------------------------------------------
__global__ __launch_bounds__(256) void wprep_kernel(const float* __restrict__ Wx,
                                                    const float* __restrict__ Wh,
                                                    const float* __restrict__ Wenc,
                                                    __bf16* __restrict__ wcat,
                                                    __bf16* __restrict__ wencf) {
    int cid = blockIdx.x * 256 + threadIdx.x;   // 200704 total
    float v[8];
    __bf16* dst;
    if (cid < 196608) {
        int widx = cid / 12288;      // 16 wgs
        int r1 = cid % 12288;
        int nn = r1 / 1536;          // np*2 + nf, 0..7
        int r2 = r1 % 1536;
        int ks = r2 >> 6, l = r2 & 63;
        int np = nn >> 1, nf = nn & 1;
        int cc = l & 15;
        int gate = (cc < 8) ? (nf ? 2 : 0) : (nf ? 3 : 1);
        int col = gate * 512 + widx * 32 + np * 8 + (cc & 7);
        int kc = ks * 32 + (l >> 4) * 8;
#pragma unroll
        for (int j = 0; j < 8; ++j) {
            int kk = kc + j;
            v[j] = (kk < DFEAT) ? Wx[kk * G4 + col] : Wh[(kk - DFEAT) * G4 + col];
        }
        dst = wcat + (size_t)cid * 8;
    } else {
        int c2 = cid - 196608;   // [0, 4096)
        int ntg = c2 >> 8;
        int r = c2 & 255;
        int ks = r >> 6, l = r & 63;
        int col = ntg * 16 + (l & 15);
        int kc = ks * 32 + (l >> 4) * 8;
#pragma unroll
        for (int j = 0; j < 8; ++j) v[j] = Wenc[(kc + j) * DFEAT + col];
        dst = wencf + (size_t)c2 * 8;
    }
    bf16x8 o;
#pragma unroll
    for (int j = 0; j < 8; ++j) o[j] = (__bf16)v[j];
    *reinterpret_cast<bf16x8*>(dst) = o;
}

// ---------------------------------------------------------------------------
// Encoder: enc[t][b][f] = tanh(x[b][t][:] @ W_enc + b_enc), bf16 out.
// ---------------------------------------------------------------------------
__global__ __launch_bounds__(256) void enc_kernel(const float* __restrict__ x,
                                                  const float* __restrict__ benc,
                                                  const __bf16* __restrict__ wencf,
                                                  __bf16* __restrict__ enc) {
    __shared__ uint4 afrag4[1024];   // 16 KB frag-linear A
    __bf16* afrag = reinterpret_cast<__bf16*>(afrag4);
    int tid = threadIdx.x;
    int lane = tid & 63, w = tid >> 6;
    int rid0 = blockIdx.x * 64;
    int ntg0 = blockIdx.y * 4;

    bf16x8 wr[4][4];
#pragma unroll
    for (int n = 0; n < 4; ++n)
#pragma unroll
        for (int ks = 0; ks < 4; ++ks)
            wr[n][ks] = *reinterpret_cast<const bf16x8*>(
                wencf + (size_t)(((ntg0 + n) * 4 + ks) * 64 + lane) * 8);
    float bias[4];
#pragma unroll
    for (int n = 0; n < 4; ++n) bias[n] = benc[(ntg0 + n) * 16 + (lane & 15)];

#pragma unroll
    for (int i = 0; i < 4; ++i) {
        int c = tid + 256 * i;          // [0,1024): row = c>>4, k8 = c&15
        int row = c >> 4, k8 = c & 15;
        const float* src = x + (size_t)(rid0 + row) * DIN + k8 * 8;
        float4 f0 = *reinterpret_cast<const float4*>(src);
        float4 f1 = *reinterpret_cast<const float4*>(src + 4);
        bf16x8 o;
        o[0] = (__bf16)f0.x; o[1] = (__bf16)f0.y; o[2] = (__bf16)f0.z; o[3] = (__bf16)f0.w;
        o[4] = (__bf16)f1.x; o[5] = (__bf16)f1.y; o[6] = (__bf16)f1.z; o[7] = (__bf16)f1.w;
        int l = (k8 & 3) * 16 + (row & 15);
        int a16 = ((row >> 4) * 4 + (k8 >> 2)) * 64 + l;
        *reinterpret_cast<bf16x8*>(afrag + (size_t)a16 * 8) = o;
    }
    __syncthreads();

    int m = w;
    f32x4 acc[4];
#pragma unroll
    for (int n = 0; n < 4; ++n) acc[n] = (f32x4){bias[n], bias[n], bias[n], bias[n]};
#pragma unroll
    for (int ks = 0; ks < 4; ++ks) {
        bf16x8 a = *reinterpret_cast<const bf16x8*>(afrag + (size_t)((m * 4 + ks) * 64 + lane) * 8);
#pragma unroll
        for (int n = 0; n < 4; ++n)
            acc[n] = __builtin_amdgcn_mfma_f32_16x16x32_bf16(a, wr[n][ks], acc[n], 0, 0, 0);
    }
#pragma unroll
    for (int n = 0; n < 4; ++n) {
        int colg = (ntg0 + n) * 16 + (lane & 15);
#pragma unroll
        for (int q = 0; q < 4; ++q) {
            int rid = rid0 + m * 16 + (lane >> 4) * 4 + q;
            int bb = rid >> 9, tt = rid & 511;
            float th = tanhfast(acc[n][q]);
            enc[(size_t)(tt * BATCH + bb) * DFEAT + colg] = (__bf16)th;
        }
    }
}

// ---------------------------------------------------------------------------
// Persistent LSTM, 16 groups x 16 wgs -- r12 base, RESCHEDULED (protocol
// byte-identical; relaxed-agent/sc1 LLC exchange, proven r2..r12):
//  1. poll at step TOP (all waves), then ISSUE h loads async, then run
//     enc MFMAs while the loads fly; one vmcnt(0) lands h + enc prefetch.
//     The h-load LLC round-trip hides under the enc MFMAs instead of
//     sitting exposed between poll and h-MFMAs.
//  2. all-wave poll removes the post-poll block barrier: 2 barriers/step.
//  Safety: LDS stores of loaded regs sit after a "memory"-clobbered waitcnt
//  asm (stores are memory ops -> cannot cross); sched_barrier(0) pins the
//  enc MFMAs above the wait (guide rule 18).
// NOTE (r3, r11): per-XCD L2 (sc0) exchange is NOT a usable coherence point
// on gfx950 (hang r3, stale-data corruption r11). LLC protocol only.
// ---------------------------------------------------------------------------
__global__ __launch_bounds__(256, 1) void lstm_kernel(const __bf16* __restrict__ enc,
                                                      const __bf16* __restrict__ wcat,
                                                      const float* __restrict__ blstm,
                                                      __bf16* __restrict__ hbuf,
                                                      unsigned int* __restrict__ flags) {
    extern __shared__ char smem[];
    __bf16* afrag = reinterpret_cast<__bf16*>(smem);

    int tid = threadIdx.x;
    int lane = tid & 63, np = tid >> 6;     // np = wave; owns 8 h-cols, all gates
    int grp = blockIdx.x & 15, widx = blockIdx.x >> 4;
    int b0 = grp * 16;
    unsigned int* myflag = &flags[(grp * 16 + widx) * 16];
    const unsigned int* pollp = &flags[(grp * 16 + (lane & 15)) * 16];

    // persistent weight frags: nf=0 -> [i|f], nf=1 -> [g|o]
    bf16x8 wreg[2][24];
#pragma unroll
    for (int nf = 0; nf < 2; ++nf)
#pragma unroll
        for (int ks = 0; ks < 24; ++ks)
            wreg[nf][ks] = *reinterpret_cast<const bf16x8*>(
                wcat + (size_t)(((((widx * 4 + np) * 2 + nf) * 24) + ks) * 64 + lane) * 8);

    const int cbase = widx * 32 + np * 8 + (lane & 7);
    const bool lo = (lane & 15) < 8;
    const float bias0 = blstm[(lo ? 0 : 1) * 512 + cbase];   // i or f col bias
    const float bias1 = blstm[(lo ? 2 : 3) * 512 + cbase];   // g or o col bias

    // ---- hoisted loop-invariant addresses (r10) ----
    const int srow16 = tid & 15;
    const int kb = (tid >> 6) * 32 + ((tid >> 4) & 3) * 8;
    const __bf16* encp = enc + (size_t)(b0 + srow16) * DFEAT + kb;
    const __bf16* hpA = hbuf + (size_t)(b0 + srow16) * DLAT + kb;   // parity 0
    const __bf16* hpB = hpA + (size_t)BATCH * DLAT;                 // parity 1
    __bf16* enc_ldsA = afrag + tid * 8;            // buf0 chunk; 2nd at +2048 elems
    __bf16* enc_ldsB = afrag + 4096 + tid * 8;     // buf1
    __bf16* h_lds    = afrag + 8192 + tid * 8;     // h chunk ii=0; +2048 elems per ii
    const __bf16* aencA = afrag + lane * 8;        // + ks*512 elems
    const __bf16* aencB = afrag + 4096 + lane * 8;
    const __bf16* ah    = afrag + 8192 + lane * 8; // + (ks-8)*512 elems

    // h store: 8B coalesced (r12): lanes l,l^2 hold adjacent 4B of row srow
    float c0 = 0.f, c1 = 0.f;
    const int srow = (lane >> 4) * 4 + (lo ? 0 : 2) + (lane & 1);
    const int scol8 = widx * 32 + np * 8 + (lane & 4);
    unsigned long long* hdA8 = reinterpret_cast<unsigned long long*>(
        hbuf + (size_t)(b0 + srow) * DLAT + scol8);                        // parity 0
    unsigned long long* hdB8 = reinterpret_cast<unsigned long long*>(
        hbuf + (size_t)BATCH * DLAT + (size_t)(b0 + srow) * DLAT + scol8); // parity 1

    // prologue: stage enc(0) into buf0
    {
        uint4 e0 = *reinterpret_cast<const uint4*>(encp);
        uint4 e1 = *reinterpret_cast<const uint4*>(encp + 128);
        *reinterpret_cast<uint4*>(enc_ldsA) = e0;
        *reinterpret_cast<uint4*>(enc_ldsA + 2048) = e1;
        encp += (size_t)BATCH * DFEAT;
    }
    __syncthreads();

#pragma unroll 1
    for (int t = 0; t < TLEN; ++t) {
        // (A) issue enc(t+1) prefetch -- async, no wait
        uint4 e0, e1;
        if (t + 1 < TLEN) {
            asm volatile(
                "global_load_dwordx4 %0, %2, off\n\t"
                "global_load_dwordx4 %1, %2, off offset:256"
                : "=&v"(e0), "=&v"(e1)
                : "v"(encp) : "memory");
        }

        uint4 d0, d1, d2, d3;
        if (t > 0) {
            // (B) all-wave poll of the group's 16 flags (relaxed agent)
            unsigned v;
            do {
                v = __hip_atomic_load(pollp, __ATOMIC_RELAXED, __HIP_MEMORY_SCOPE_AGENT);
            } while (!__all((int)(v >= (unsigned)t)));

            // (C) issue h(t) loads -- async, no wait; fly across enc MFMAs
            const __bf16* hp = (t & 1) ? hpB : hpA;
            asm volatile(
                "global_load_dwordx4 %0, %4, off sc1\n\t"
                "global_load_dwordx4 %1, %4, off offset:256 sc1\n\t"
                "global_load_dwordx4 %2, %4, off offset:512 sc1\n\t"
                "global_load_dwordx4 %3, %4, off offset:768 sc1"
                : "=&v"(d0), "=&v"(d1), "=&v"(d2), "=&v"(d3)
                : "v"(hp) : "memory");
        }

        // (D) enc-part MFMAs (ks 0..7), split even/odd accumulator chains --
        //     overlaps the in-flight h loads
        f32x4 acc0e = (f32x4){bias0, bias0, bias0, bias0};
        f32x4 acc1e = (f32x4){bias1, bias1, bias1, bias1};
        f32x4 acc0o = (f32x4){0.f, 0.f, 0.f, 0.f};
        f32x4 acc1o = (f32x4){0.f, 0.f, 0.f, 0.f};
        const __bf16* aenc = (t & 1) ? aencB : aencA;
#pragma unroll
        for (int ks = 0; ks < 8; ks += 2) {
            bf16x8 a0 = *reinterpret_cast<const bf16x8*>(aenc + ks * 512);
            bf16x8 a1 = *reinterpret_cast<const bf16x8*>(aenc + (ks + 1) * 512);
            acc0e = __builtin_amdgcn_mfma_f32_16x16x32_bf16(a0, wreg[0][ks], acc0e, 0, 0, 0);
            acc1e = __builtin_amdgcn_mfma_f32_16x16x32_bf16(a0, wreg[1][ks], acc1e, 0, 0, 0);
            acc0o = __builtin_amdgcn_mfma_f32_16x16x32_bf16(a1, wreg[0][ks + 1], acc0o, 0, 0, 0);
            acc1o = __builtin_amdgcn_mfma_f32_16x16x32_bf16(a1, wreg[1][ks + 1], acc1o, 0, 0, 0);
        }
        __builtin_amdgcn_sched_barrier(0);   // pin MFMAs above the wait

        // (E) land h + enc prefetch; LDS stores cannot cross the clobber
        asm volatile("s_waitcnt vmcnt(0)" ::: "memory");
        if (t > 0) {
            *reinterpret_cast<uint4*>(h_lds) = d0;
            *reinterpret_cast<uint4*>(h_lds + 2048) = d1;
            *reinterpret_cast<uint4*>(h_lds + 4096) = d2;
            *reinterpret_cast<uint4*>(h_lds + 6144) = d3;
        }
        if (t + 1 < TLEN) {
            __bf16* ed = ((t + 1) & 1) ? enc_ldsB : enc_ldsA;
            *reinterpret_cast<uint4*>(ed) = e0;
            *reinterpret_cast<uint4*>(ed + 2048) = e1;
            encp += (size_t)BATCH * DFEAT;
        }
        __syncthreads();   // b1: h frags + next enc visible block-wide

        if (t > 0) {
            // (F) h-part MFMAs (ks 8..23), split chains
#pragma unroll
            for (int ks = 8; ks < 24; ks += 2) {
                bf16x8 a0 = *reinterpret_cast<const bf16x8*>(ah + (ks - 8) * 512);
                bf16x8 a1 = *reinterpret_cast<const bf16x8*>(ah + (ks - 7) * 512);
                acc0e = __builtin_amdgcn_mfma_f32_16x16x32_bf16(a0, wreg[0][ks], acc0e, 0, 0, 0);
                acc1e = __builtin_amdgcn_mfma_f32_16x16x32_bf16(a0, wreg[1][ks], acc1e, 0, 0, 0);
                acc0o = __builtin_amdgcn_mfma_f32_16x16x32_bf16(a1, wreg[0][ks + 1], acc0o, 0, 0, 0);
                acc1o = __builtin_amdgcn_mfma_f32_16x16x32_bf16(a1, wreg[1][ks + 1], acc1o, 0, 0, 0);
            }
        }
        f32x4 z0 = acc0e + acc0o;
        f32x4 z1 = acc1e + acc1o;

        // (G) in-wave gate exchange (r9-proven)
        float p00 = __shfl_xor(z0[0], 8), p01 = __shfl_xor(z0[1], 8);
        float p02 = __shfl_xor(z0[2], 8), p03 = __shfl_xor(z0[3], 8);
        float p10 = __shfl_xor(z1[0], 8), p11 = __shfl_xor(z1[1], 8);
        float p12 = __shfl_xor(z1[2], 8), p13 = __shfl_xor(z1[3], 8);

        float zi_a = lo ? z0[0] : p02, zf_a = lo ? p00 : z0[2];
        float zg_a = lo ? z1[0] : p12, zo_a = lo ? p10 : z1[2];
        float zi_b = lo ? z0[1] : p03, zf_b = lo ? p01 : z0[3];
        float zg_b = lo ? z1[1] : p13, zo_b = lo ? p11 : z1[3];

        float ia = sigf(zi_a), fa = sigf(zf_a), ga = tanhfast(zg_a), oa = sigf(zo_a);
        c0 = fa * c0 + ia * ga;
        float h_a = oa * tanhfast(c0);
        float ib = sigf(zi_b), fb = sigf(zf_b), gb = tanhfast(zg_b), ob = sigf(zo_b);
        c1 = fb * c1 + ib * gb;
        float h_b = ob * tanhfast(c1);

        // (H) re-pair adjacent columns via lane^1, assemble 8B via lane^2,
        //     store from lane&2==0 -- r5-proven u64 relaxed-agent primitive
        unsigned sendv = (lane & 1) ? (unsigned)bfb(h_a) : (unsigned)bfb(h_b);
        unsigned recv = (unsigned)__shfl_xor((int)sendv, 1);
        unsigned word = (lane & 1) ? (recv | ((unsigned)bfb(h_b) << 16))
                                   : ((unsigned)bfb(h_a) | (recv << 16));
        unsigned word2 = (unsigned)__shfl_xor((int)word, 2);
        if ((lane & 2) == 0) {
            unsigned long long w8 =
                (unsigned long long)word | ((unsigned long long)word2 << 32);
            __hip_atomic_store(((t & 1) ? hdA8 : hdB8), w8, __ATOMIC_RELAXED,
                               __HIP_MEMORY_SCOPE_AGENT);
        }

        // (I) release: __syncthreads drains each wave's vmcnt(0) -> stores
        // LLC-visible; then publish own flag (independent line per wg).
        __syncthreads();   // b2
        if (tid == 0)
            __hip_atomic_store(myflag, (unsigned int)(t + 1), __ATOMIC_RELAXED,
                               __HIP_MEMORY_SCOPE_AGENT);
    }
}

// ---------------------------------------------------------------------------
// Decoder: out[b] = h_last[b,:] @ W_dec + b_dec. h_last is hbuf[0] (T even).
// ---------------------------------------------------------------------------
__global__ __launch_bounds__(64) void dec_kernel(const __bf16* __restrict__ hbuf,
                                                 const float* __restrict__ wdec,
                                                 const float* __restrict__ bdec,
                                                 float* __restrict__ out) {
    int b = blockIdx.x, lane = threadIdx.x;
    uint4 d = *reinterpret_cast<const uint4*>(hbuf + (size_t)b * DLAT + lane * 8);
    const __bf16* hv = reinterpret_cast<const __bf16*>(&d);
    float4 w0 = *reinterpret_cast<const float4*>(wdec + lane * 8);
    float4 w1 = *reinterpret_cast<const float4*>(wdec + lane * 8 + 4);
    float s = (float)hv[0] * w0.x + (float)hv[1] * w0.y + (float)hv[2] * w0.z +
              (float)hv[3] * w0.w + (float)hv[4] * w1.x + (float)hv[5] * w1.y +
              (float)hv[6] * w1.z + (float)hv[7] * w1.w;
#pragma unroll
    for (int off = 32; off; off >>= 1) s += __shfl_xor(s, off);
    if (lane == 0) out[b] = s + bdec[0];
}

extern "C" void kernel_launch(void* const* d_in, const int* in_sizes, int n_in,
                              void* d_out, int out_size, void* d_ws, size_t ws_size,
                              hipStream_t stream) {
    (void)in_sizes; (void)n_in; (void)out_size; (void)ws_size;
    const float* x     = (const float*)d_in[0];
    const float* Wenc  = (const float*)d_in[1];
    const float* benc  = (const float*)d_in[2];
    const float* Wx    = (const float*)d_in[3];
    const float* Wh    = (const float*)d_in[4];
    const float* blstm = (const float*)d_in[5];
    const float* Wdec  = (const float*)d_in[6];
    const float* bdec  = (const float*)d_in[7];

    char* ws = (char*)d_ws;
    __bf16* wcat  = (__bf16*)(ws + WCAT_OFF);
    __bf16* wencf = (__bf16*)(ws + WENC_OFF);
    __bf16* enc   = (__bf16*)(ws + ENC_OFF);
    __bf16* hbuf  = (__bf16*)(ws + H_OFF);
    unsigned int* flags = (unsigned int*)(ws + FLAG_OFF);

    // zero the per-wg flags each call (deterministic across graph replays)
    (void)hipMemsetAsync(ws + FLAG_OFF, 0, 16384, stream);

    wprep_kernel<<<784, 256, 0, stream>>>(Wx, Wh, Wenc, wcat, wencf);
    enc_kernel<<<dim3(2048, 4), 256, 0, stream>>>(x, benc, wencf, enc);

    // 90 KB dynamic LDS forces 1 block/CU (256 blocks on 256 CUs).
    (void)hipFuncSetAttribute(reinterpret_cast<const void*>(lstm_kernel),
                              hipFuncAttributeMaxDynamicSharedMemorySize, 90112);
    lstm_kernel<<<256, 256, 90112, stream>>>(enc, wcat, blstm, hbuf, flags);

    dec_kernel<<<256, 64, 0, stream>>>(hbuf, Wdec, bdec, (float*)d_out);
}

// Round 14
// 1279.410 us; speedup vs baseline: 1.0444x; 1.0444x over previous
//
#include <hip/hip_runtime.h>

// Problem dims
#define BATCH 256
#define TLEN  512
#define DIN   128
#define DFEAT 256
#define DLAT  512
#define G4    2048   // 4*DLAT
#define KCAT  768    // DFEAT + DLAT

typedef __bf16 bf16x8 __attribute__((ext_vector_type(8)));
typedef float f32x4 __attribute__((ext_vector_type(4)));

// ws layout (bytes) -- identical to round 6/9/10/12 (proven)
#define WCAT_OFF   0u          // 768x2048 bf16 frag-linear: 3,145,728
#define WENC_OFF   3145728u    // 128x256  bf16 frag-linear: 65,536
#define ENC_OFF    3211264u    // enc bf16 [T][B][256]: 67,108,864
#define H_OFF      70320128u   // h dbuf bf16 [2][256][512]: 524,288
#define FLAG_OFF   70844416u   // flags: (grp*16+widx)*16 uints (64B lines): 16,384

__device__ __forceinline__ float sigf(float x)  { return 1.0f / (1.0f + __expf(-x)); }
__device__ __forceinline__ float tanhfast(float x){ return 2.0f / (1.0f + __expf(-2.0f * x)) - 1.0f; }
__device__ __forceinline__ unsigned short bfb(float f) {
    __bf16 b = (__bf16)f;
    return __builtin_bit_cast(unsigned short, b);
}

// ---------------------------------------------------------------------------
// Weight prep: bf16 fragment-linear copies of [W_x;W_h] (768x2048) and W_enc.
// wcat layout (wave-owns-all-gates, r9-proven): chunk cid = ((((widx*4 + np)
// *2 + nf)*24 + ks)*64 + l) holds B[k = ks*32+(l>>4)*8 .. +8][col] with
//   cc = l&15;  gate = (cc<8) ? (nf?2:0) : (nf?3:1);
//   col = gate*512 + widx*32 + np*8 + (cc&7).
// ---------------------------------------------------------------------------
__global__ __launch_bounds__(256) void wprep_kernel(const float* __restrict__ Wx,
                                                    const float* __restrict__ Wh,
                                                    const float* __restrict__ Wenc,
                                                    __bf16* __restrict__ wcat,
                                                    __bf16* __restrict__ wencf) {
    int cid = blockIdx.x * 256 + threadIdx.x;   // 200704 total
    float v[8];
    __bf16* dst;
    if (cid < 196608) {
        int widx = cid / 12288;      // 16 wgs
        int r1 = cid % 12288;
        int nn = r1 / 1536;          // np*2 + nf, 0..7
        int r2 = r1 % 1536;
        int ks = r2 >> 6, l = r2 & 63;
        int np = nn >> 1, nf = nn & 1;
        int cc = l & 15;
        int gate = (cc < 8) ? (nf ? 2 : 0) : (nf ? 3 : 1);
        int col = gate * 512 + widx * 32 + np * 8 + (cc & 7);
        int kc = ks * 32 + (l >> 4) * 8;
#pragma unroll
        for (int j = 0; j < 8; ++j) {
            int kk = kc + j;
            v[j] = (kk < DFEAT) ? Wx[kk * G4 + col] : Wh[(kk - DFEAT) * G4 + col];
        }
        dst = wcat + (size_t)cid * 8;
    } else {
        int c2 = cid - 196608;   // [0, 4096)
        int ntg = c2 >> 8;
        int r = c2 & 255;
        int ks = r >> 6, l = r & 63;
        int col = ntg * 16 + (l & 15);
        int kc = ks * 32 + (l >> 4) * 8;
#pragma unroll
        for (int j = 0; j < 8; ++j) v[j] = Wenc[(kc + j) * DFEAT + col];
        dst = wencf + (size_t)c2 * 8;
    }
    bf16x8 o;
#pragma unroll
    for (int j = 0; j < 8; ++j) o[j] = (__bf16)v[j];
    *reinterpret_cast<bf16x8*>(dst) = o;
}

// ---------------------------------------------------------------------------
// Encoder: enc[t][b][f] = tanh(x[b][t][:] @ W_enc + b_enc), bf16 out.
// ---------------------------------------------------------------------------
__global__ __launch_bounds__(256) void enc_kernel(const float* __restrict__ x,
                                                  const float* __restrict__ benc,
                                                  const __bf16* __restrict__ wencf,
                                                  __bf16* __restrict__ enc) {
    __shared__ uint4 afrag4[1024];   // 16 KB frag-linear A
    __bf16* afrag = reinterpret_cast<__bf16*>(afrag4);
    int tid = threadIdx.x;
    int lane = tid & 63, w = tid >> 6;
    int rid0 = blockIdx.x * 64;
    int ntg0 = blockIdx.y * 4;

    bf16x8 wr[4][4];
#pragma unroll
    for (int n = 0; n < 4; ++n)
#pragma unroll
        for (int ks = 0; ks < 4; ++ks)
            wr[n][ks] = *reinterpret_cast<const bf16x8*>(
                wencf + (size_t)(((ntg0 + n) * 4 + ks) * 64 + lane) * 8);
    float bias[4];
#pragma unroll
    for (int n = 0; n < 4; ++n) bias[n] = benc[(ntg0 + n) * 16 + (lane & 15)];

#pragma unroll
    for (int i = 0; i < 4; ++i) {
        int c = tid + 256 * i;          // [0,1024): row = c>>4, k8 = c&15
        int row = c >> 4, k8 = c & 15;
        const float* src = x + (size_t)(rid0 + row) * DIN + k8 * 8;
        float4 f0 = *reinterpret_cast<const float4*>(src);
        float4 f1 = *reinterpret_cast<const float4*>(src + 4);
        bf16x8 o;
        o[0] = (__bf16)f0.x; o[1] = (__bf16)f0.y; o[2] = (__bf16)f0.z; o[3] = (__bf16)f0.w;
        o[4] = (__bf16)f1.x; o[5] = (__bf16)f1.y; o[6] = (__bf16)f1.z; o[7] = (__bf16)f1.w;
        int l = (k8 & 3) * 16 + (row & 15);
        int a16 = ((row >> 4) * 4 + (k8 >> 2)) * 64 + l;
        *reinterpret_cast<bf16x8*>(afrag + (size_t)a16 * 8) = o;
    }
    __syncthreads();

    int m = w;
    f32x4 acc[4];
#pragma unroll
    for (int n = 0; n < 4; ++n) acc[n] = (f32x4){bias[n], bias[n], bias[n], bias[n]};
#pragma unroll
    for (int ks = 0; ks < 4; ++ks) {
        bf16x8 a = *reinterpret_cast<const bf16x8*>(afrag + (size_t)((m * 4 + ks) * 64 + lane) * 8);
#pragma unroll
        for (int n = 0; n < 4; ++n)
            acc[n] = __builtin_amdgcn_mfma_f32_16x16x32_bf16(a, wr[n][ks], acc[n], 0, 0, 0);
    }
#pragma unroll
    for (int n = 0; n < 4; ++n) {
        int colg = (ntg0 + n) * 16 + (lane & 15);
#pragma unroll
        for (int q = 0; q < 4; ++q) {
            int rid = rid0 + m * 16 + (lane >> 4) * 4 + q;
            int bb = rid >> 9, tt = rid & 511;
            float th = tanhfast(acc[n][q]);
            enc[(size_t)(tt * BATCH + bb) * DFEAT + colg] = (__bf16)th;
        }
    }
}

// ---------------------------------------------------------------------------
// Persistent LSTM, 16 groups x 16 wgs -- r12 optimum, restored verbatim.
// Chain-floor note (r13 post-mortem): enc-MFMAs (~400cy) can hide EITHER the
// poll-wait (~900cy, r12 order) OR the h-load RT (~900cy, r13 order), never
// both -- the schedules are equivalent, and r13's all-wave poll cost -5%.
// Step floor = ~4 serialized LLC transactions + compute = ~2.45us/step.
// NOTE (r3, r11): per-XCD L2 (sc0) exchange is NOT a usable coherence point
// on gfx950 (hang r3, stale-data corruption r11). LLC protocol only.
// ---------------------------------------------------------------------------
__global__ __launch_bounds__(256, 1) void lstm_kernel(const __bf16* __restrict__ enc,
                                                      const __bf16* __restrict__ wcat,
                                                      const float* __restrict__ blstm,
                                                      __bf16* __restrict__ hbuf,
                                                      unsigned int* __restrict__ flags) {
    extern __shared__ char smem[];
    __bf16* afrag = reinterpret_cast<__bf16*>(smem);

    int tid = threadIdx.x;
    int lane = tid & 63, np = tid >> 6;     // np = wave; owns 8 h-cols, all gates
    int grp = blockIdx.x & 15, widx = blockIdx.x >> 4;
    int b0 = grp * 16;
    unsigned int* myflag = &flags[(grp * 16 + widx) * 16];

    // persistent weight frags: nf=0 -> [i|f], nf=1 -> [g|o]
    bf16x8 wreg[2][24];
#pragma unroll
    for (int nf = 0; nf < 2; ++nf)
#pragma unroll
        for (int ks = 0; ks < 24; ++ks)
            wreg[nf][ks] = *reinterpret_cast<const bf16x8*>(
                wcat + (size_t)(((((widx * 4 + np) * 2 + nf) * 24) + ks) * 64 + lane) * 8);

    const int cbase = widx * 32 + np * 8 + (lane & 7);
    const bool lo = (lane & 15) < 8;
    const float bias0 = blstm[(lo ? 0 : 1) * 512 + cbase];   // i or f col bias
    const float bias1 = blstm[(lo ? 2 : 3) * 512 + cbase];   // g or o col bias

    // ---- hoisted loop-invariant addresses (r10) ----
    const int srow16 = tid & 15;
    const int kb = (tid >> 6) * 32 + ((tid >> 4) & 3) * 8;
    const __bf16* encp = enc + (size_t)(b0 + srow16) * DFEAT + kb;
    const __bf16* hpA = hbuf + (size_t)(b0 + srow16) * DLAT + kb;   // parity 0
    const __bf16* hpB = hpA + (size_t)BATCH * DLAT;                 // parity 1
    __bf16* enc_ldsA = afrag + tid * 8;            // buf0 chunk; 2nd at +2048 elems
    __bf16* enc_ldsB = afrag + 4096 + tid * 8;     // buf1
    __bf16* h_lds    = afrag + 8192 + tid * 8;     // h chunk ii=0; +2048 elems per ii
    const __bf16* aencA = afrag + lane * 8;        // + ks*512 elems
    const __bf16* aencB = afrag + 4096 + lane * 8;
    const __bf16* ah    = afrag + 8192 + lane * 8; // + (ks-8)*512 elems

    // h store: lanes l,l^2 hold adjacent 4B of row srow (srow ignores bit1);
    // lane&2==0 lanes store 8B at col scol8 (r12 coalescing)
    float c0 = 0.f, c1 = 0.f;
    const int srow = (lane >> 4) * 4 + (lo ? 0 : 2) + (lane & 1);
    const int scol8 = widx * 32 + np * 8 + (lane & 4);
    unsigned long long* hdA8 = reinterpret_cast<unsigned long long*>(
        hbuf + (size_t)(b0 + srow) * DLAT + scol8);                        // parity 0
    unsigned long long* hdB8 = reinterpret_cast<unsigned long long*>(
        hbuf + (size_t)BATCH * DLAT + (size_t)(b0 + srow) * DLAT + scol8); // parity 1

    // prologue: stage enc(0) into buf0
    {
        uint4 e0 = *reinterpret_cast<const uint4*>(encp);
        uint4 e1 = *reinterpret_cast<const uint4*>(encp + 128);
        *reinterpret_cast<uint4*>(enc_ldsA) = e0;
        *reinterpret_cast<uint4*>(enc_ldsA + 2048) = e1;
        encp += (size_t)BATCH * DFEAT;
    }
    __syncthreads();

#pragma unroll 1
    for (int t = 0; t < TLEN; ++t) {
        // (0) issue enc(t+1) prefetch -- no waitcnt; flies across this step
        uint4 e0, e1;
        if (t + 1 < TLEN) {
            asm volatile(
                "global_load_dwordx4 %0, %2, off\n\t"
                "global_load_dwordx4 %1, %2, off offset:256"
                : "=&v"(e0), "=&v"(e1)
                : "v"(encp) : "memory");
        }

        // (1) enc-part MFMAs (ks 0..7), split even/odd accumulator chains
        f32x4 acc0e = (f32x4){bias0, bias0, bias0, bias0};
        f32x4 acc1e = (f32x4){bias1, bias1, bias1, bias1};
        f32x4 acc0o = (f32x4){0.f, 0.f, 0.f, 0.f};
        f32x4 acc1o = (f32x4){0.f, 0.f, 0.f, 0.f};
        const __bf16* aenc = (t & 1) ? aencB : aencA;
#pragma unroll
        for (int ks = 0; ks < 8; ks += 2) {
            bf16x8 a0 = *reinterpret_cast<const bf16x8*>(aenc + ks * 512);
            bf16x8 a1 = *reinterpret_cast<const bf16x8*>(aenc + (ks + 1) * 512);
            acc0e = __builtin_amdgcn_mfma_f32_16x16x32_bf16(a0, wreg[0][ks], acc0e, 0, 0, 0);
            acc1e = __builtin_amdgcn_mfma_f32_16x16x32_bf16(a0, wreg[1][ks], acc1e, 0, 0, 0);
            acc0o = __builtin_amdgcn_mfma_f32_16x16x32_bf16(a1, wreg[0][ks + 1], acc0o, 0, 0, 0);
            acc1o = __builtin_amdgcn_mfma_f32_16x16x32_bf16(a1, wreg[1][ks + 1], acc1o, 0, 0, 0);
        }

        if (t > 0) {
            // (2) acquire: wave 0 polls the group's 16 flags (r6-proven)
            if (tid < 64) {
                const unsigned int* f = &flags[(grp * 16 + (lane & 15)) * 16];
                unsigned v;
                do {
                    v = __hip_atomic_load(f, __ATOMIC_RELAXED, __HIP_MEMORY_SCOPE_AGENT);
                } while (!__all((int)(v >= (unsigned)t)));
            }
            __syncthreads();   // b2

            // (3) h(t) slice: 4x16B sc1 loads off one base (+imm offsets)
            const __bf16* hp = (t & 1) ? hpB : hpA;
            uint4 d0, d1, d2, d3;
            asm volatile(
                "global_load_dwordx4 %0, %4, off sc1\n\t"
                "global_load_dwordx4 %1, %4, off offset:256 sc1\n\t"
                "global_load_dwordx4 %2, %4, off offset:512 sc1\n\t"
                "global_load_dwordx4 %3, %4, off offset:768 sc1\n\t"
                "s_waitcnt vmcnt(0)"
                : "=&v"(d0), "=&v"(d1), "=&v"(d2), "=&v"(d3)
                : "v"(hp) : "memory");
            *reinterpret_cast<uint4*>(h_lds) = d0;
            *reinterpret_cast<uint4*>(h_lds + 2048) = d1;
            *reinterpret_cast<uint4*>(h_lds + 4096) = d2;
            *reinterpret_cast<uint4*>(h_lds + 6144) = d3;
        }

        // (4) land enc(t+1) prefetch into the alternate buffer
        asm volatile("s_waitcnt vmcnt(0)" ::: "memory");   // free if (3) ran
        if (t + 1 < TLEN) {
            __bf16* ed = ((t + 1) & 1) ? enc_ldsB : enc_ldsA;
            *reinterpret_cast<uint4*>(ed) = e0;
            *reinterpret_cast<uint4*>(ed + 2048) = e1;
            encp += (size_t)BATCH * DFEAT;
        }
        __syncthreads();   // b3: h frags + next enc visible block-wide

        if (t > 0) {
            // (5) h-part MFMAs (ks 8..23), split chains
#pragma unroll
            for (int ks = 8; ks < 24; ks += 2) {
                bf16x8 a0 = *reinterpret_cast<const bf16x8*>(ah + (ks - 8) * 512);
                bf16x8 a1 = *reinterpret_cast<const bf16x8*>(ah + (ks - 7) * 512);
                acc0e = __builtin_amdgcn_mfma_f32_16x16x32_bf16(a0, wreg[0][ks], acc0e, 0, 0, 0);
                acc1e = __builtin_amdgcn_mfma_f32_16x16x32_bf16(a0, wreg[1][ks], acc1e, 0, 0, 0);
                acc0o = __builtin_amdgcn_mfma_f32_16x16x32_bf16(a1, wreg[0][ks + 1], acc0o, 0, 0, 0);
                acc1o = __builtin_amdgcn_mfma_f32_16x16x32_bf16(a1, wreg[1][ks + 1], acc1o, 0, 0, 0);
            }
        }
        f32x4 z0 = acc0e + acc0o;
        f32x4 z1 = acc1e + acc1o;

        // (6) in-wave gate exchange (r9-proven)
        float p00 = __shfl_xor(z0[0], 8), p01 = __shfl_xor(z0[1], 8);
        float p02 = __shfl_xor(z0[2], 8), p03 = __shfl_xor(z0[3], 8);
        float p10 = __shfl_xor(z1[0], 8), p11 = __shfl_xor(z1[1], 8);
        float p12 = __shfl_xor(z1[2], 8), p13 = __shfl_xor(z1[3], 8);

        float zi_a = lo ? z0[0] : p02, zf_a = lo ? p00 : z0[2];
        float zg_a = lo ? z1[0] : p12, zo_a = lo ? p10 : z1[2];
        float zi_b = lo ? z0[1] : p03, zf_b = lo ? p01 : z0[3];
        float zg_b = lo ? z1[1] : p13, zo_b = lo ? p11 : z1[3];

        float ia = sigf(zi_a), fa = sigf(zf_a), ga = tanhfast(zg_a), oa = sigf(zo_a);
        c0 = fa * c0 + ia * ga;
        float h_a = oa * tanhfast(c0);
        float ib = sigf(zi_b), fb = sigf(zf_b), gb = tanhfast(zg_b), ob = sigf(zo_b);
        c1 = fb * c1 + ib * gb;
        float h_b = ob * tanhfast(c1);

        // (7) re-pair adjacent columns via lane^1 (r9-proven), then assemble
        // 8B per lane-pair via lane^2 (same row: srow ignores bit1) and store
        // from lanes with lane&2==0 -- r5-proven u64 relaxed-agent primitive.
        unsigned sendv = (lane & 1) ? (unsigned)bfb(h_a) : (unsigned)bfb(h_b);
        unsigned recv = (unsigned)__shfl_xor((int)sendv, 1);
        unsigned word = (lane & 1) ? (recv | ((unsigned)bfb(h_b) << 16))
                                   : ((unsigned)bfb(h_a) | (recv << 16));
        unsigned word2 = (unsigned)__shfl_xor((int)word, 2);
        if ((lane & 2) == 0) {
            unsigned long long w8 =
                (unsigned long long)word | ((unsigned long long)word2 << 32);
            __hip_atomic_store(((t & 1) ? hdA8 : hdB8), w8, __ATOMIC_RELAXED,
                               __HIP_MEMORY_SCOPE_AGENT);
        }

        // (8) release: __syncthreads drains each wave's vmcnt(0) -> stores
        // LLC-visible; then publish own flag (independent line per wg).
        __syncthreads();   // b4
        if (tid == 0)
            __hip_atomic_store(myflag, (unsigned int)(t + 1), __ATOMIC_RELAXED,
                               __HIP_MEMORY_SCOPE_AGENT);
    }
}

// ---------------------------------------------------------------------------
// Decoder: out[b] = h_last[b,:] @ W_dec + b_dec. h_last is hbuf[0] (T even).
// ---------------------------------------------------------------------------
__global__ __launch_bounds__(64) void dec_kernel(const __bf16* __restrict__ hbuf,
                                                 const float* __restrict__ wdec,
                                                 const float* __restrict__ bdec,
                                                 float* __restrict__ out) {
    int b = blockIdx.x, lane = threadIdx.x;
    uint4 d = *reinterpret_cast<const uint4*>(hbuf + (size_t)b * DLAT + lane * 8);
    const __bf16* hv = reinterpret_cast<const __bf16*>(&d);
    float4 w0 = *reinterpret_cast<const float4*>(wdec + lane * 8);
    float4 w1 = *reinterpret_cast<const float4*>(wdec + lane * 8 + 4);
    float s = (float)hv[0] * w0.x + (float)hv[1] * w0.y + (float)hv[2] * w0.z +
              (float)hv[3] * w0.w + (float)hv[4] * w1.x + (float)hv[5] * w1.y +
              (float)hv[6] * w1.z + (float)hv[7] * w1.w;
#pragma unroll
    for (int off = 32; off; off >>= 1) s += __shfl_xor(s, off);
    if (lane == 0) out[b] = s + bdec[0];
}

extern "C" void kernel_launch(void* const* d_in, const int* in_sizes, int n_in,
                              void* d_out, int out_size, void* d_ws, size_t ws_size,
                              hipStream_t stream) {
    (void)in_sizes; (void)n_in; (void)out_size; (void)ws_size;
    const float* x     = (const float*)d_in[0];
    const float* Wenc  = (const float*)d_in[1];
    const float* benc  = (const float*)d_in[2];
    const float* Wx    = (const float*)d_in[3];
    const float* Wh    = (const float*)d_in[4];
    const float* blstm = (const float*)d_in[5];
    const float* Wdec  = (const float*)d_in[6];
    const float* bdec  = (const float*)d_in[7];

    char* ws = (char*)d_ws;
    __bf16* wcat  = (__bf16*)(ws + WCAT_OFF);
    __bf16* wencf = (__bf16*)(ws + WENC_OFF);
    __bf16* enc   = (__bf16*)(ws + ENC_OFF);
    __bf16* hbuf  = (__bf16*)(ws + H_OFF);
    unsigned int* flags = (unsigned int*)(ws + FLAG_OFF);

    // zero the per-wg flags each call (deterministic across graph replays)
    (void)hipMemsetAsync(ws + FLAG_OFF, 0, 16384, stream);

    wprep_kernel<<<784, 256, 0, stream>>>(Wx, Wh, Wenc, wcat, wencf);
    enc_kernel<<<dim3(2048, 4), 256, 0, stream>>>(x, benc, wencf, enc);

    // 90 KB dynamic LDS forces 1 block/CU (256 blocks on 256 CUs).
    (void)hipFuncSetAttribute(reinterpret_cast<const void*>(lstm_kernel),
                              hipFuncAttributeMaxDynamicSharedMemorySize, 90112);
    lstm_kernel<<<256, 256, 90112, stream>>>(enc, wcat, blstm, hbuf, flags);

    dec_kernel<<<256, 64, 0, stream>>>(hbuf, Wdec, bdec, (float*)d_out);
}